// Round 2
// baseline (5845.816 us; speedup 1.0000x reference)
//
#include <hip/hip_runtime.h>

// N = 100000 nodes, E = 1600000 edges, IN=128, HID=128, LAT=64
// edge_index is pushed to device as int32 (harness converts integer inputs).

// ---------------- degree: deg[dst] += 1 ----------------
__global__ void k_degree(const int* __restrict__ dst, float* __restrict__ deg, int E, int nNodes) {
    int i = blockIdx.x * blockDim.x + threadIdx.x;
    if (i < E) {
        unsigned d = (unsigned)dst[i];
        if (d < (unsigned)nNodes) atomicAdd(&deg[d], 1.0f);
    }
}

// ---------------- feature scatter: msg[dst] += feat[src], 128 ch ----------------
// 32 threads per edge, each handles 4 channels (float4 gather + 4 f32 atomics)
__global__ void k_scatter128(const int* __restrict__ src, const int* __restrict__ dst,
                             const float* __restrict__ feat, float* __restrict__ msg,
                             int E, int nNodes) {
    int t = blockIdx.x * blockDim.x + threadIdx.x;
    int total = E * 32;
    if (t >= total) return;
    int e = t >> 5;
    int j = t & 31;
    unsigned s = (unsigned)src[e];
    unsigned d = (unsigned)dst[e];
    if (s >= (unsigned)nNodes || d >= (unsigned)nNodes) return;
    float4 v = ((const float4*)feat)[(long long)s * 32 + j];
    float* p = &msg[(long long)d * 128 + j * 4];
    atomicAdd(p + 0, v.x);
    atomicAdd(p + 1, v.y);
    atomicAdd(p + 2, v.z);
    atomicAdd(p + 3, v.w);
}

// ---------------- SAGE layer 1: h = relu( (msg*deg_inv)@Wl^T + bl + x@Wr^T ) ----------------
// 32 nodes / block; 256 threads = 128 ch x 2 node-groups; 16 nodes per thread.
__launch_bounds__(256)
__global__ void k_sage1(const float* __restrict__ x, const float* __restrict__ msg,
                        const float* __restrict__ deg,
                        const float* __restrict__ Wl, const float* __restrict__ bl,
                        const float* __restrict__ Wr,
                        float* __restrict__ h, int nNodes) {
    __shared__ float xs[32][128];
    __shared__ float ms[32][128];
    int tid = threadIdx.x;
    int base = blockIdx.x * 32;

    for (int i = tid; i < 32 * 32; i += 256) {   // 1024 float4 per array
        int row = i >> 5, col4 = i & 31;
        int n = base + row;
        float4 xv = make_float4(0.f, 0.f, 0.f, 0.f), mv = xv;
        if (n < nNodes) {
            xv = ((const float4*)x)[(long long)n * 32 + col4];
            mv = ((const float4*)msg)[(long long)n * 32 + col4];
            float di = 1.0f / fmaxf(deg[n], 1.0f);
            mv.x *= di; mv.y *= di; mv.z *= di; mv.w *= di;
        }
        ((float4*)&xs[row][0])[col4] = xv;
        ((float4*)&ms[row][0])[col4] = mv;
    }
    __syncthreads();

    int ch = tid & 127;
    int g  = tid >> 7;           // 0..1
    float acc[16];
#pragma unroll
    for (int i = 0; i < 16; ++i) acc[i] = 0.f;

    const float4* wr = (const float4*)&Wr[ch * 128];
    const float4* wl = (const float4*)&Wl[ch * 128];
    for (int kc = 0; kc < 32; ++kc) {
        float4 wr4 = wr[kc];
        float4 wl4 = wl[kc];
#pragma unroll
        for (int i = 0; i < 16; ++i) {
            int row = g * 16 + i;
            float4 xv = ((const float4*)&xs[row][0])[kc];
            float4 mv = ((const float4*)&ms[row][0])[kc];
            acc[i] += xv.x * wr4.x + xv.y * wr4.y + xv.z * wr4.z + xv.w * wr4.w
                    + mv.x * wl4.x + mv.y * wl4.y + mv.z * wl4.z + mv.w * wl4.w;
        }
    }
    float bias = bl[ch];
#pragma unroll
    for (int i = 0; i < 16; ++i) {
        int n = base + g * 16 + i;
        if (n < nNodes) {
            float v = acc[i] + bias;
            h[(long long)n * 128 + ch] = fmaxf(v, 0.f);
        }
    }
}

// ---------------- SAGE layer 2: z = (msg*deg_inv)@Wl^T + bl + h@Wr^T (no relu) ----------------
// 32 nodes / block; 256 threads = 64 ch x 4 node-groups; 8 nodes per thread.
__launch_bounds__(256)
__global__ void k_sage2(const float* __restrict__ h, const float* __restrict__ msg,
                        const float* __restrict__ deg,
                        const float* __restrict__ Wl, const float* __restrict__ bl,
                        const float* __restrict__ Wr,
                        float* __restrict__ z, int nNodes) {
    __shared__ float xs[32][128];
    __shared__ float ms[32][128];
    int tid = threadIdx.x;
    int base = blockIdx.x * 32;

    for (int i = tid; i < 32 * 32; i += 256) {
        int row = i >> 5, col4 = i & 31;
        int n = base + row;
        float4 xv = make_float4(0.f, 0.f, 0.f, 0.f), mv = xv;
        if (n < nNodes) {
            xv = ((const float4*)h)[(long long)n * 32 + col4];
            mv = ((const float4*)msg)[(long long)n * 32 + col4];
            float di = 1.0f / fmaxf(deg[n], 1.0f);
            mv.x *= di; mv.y *= di; mv.z *= di; mv.w *= di;
        }
        ((float4*)&xs[row][0])[col4] = xv;
        ((float4*)&ms[row][0])[col4] = mv;
    }
    __syncthreads();

    int ch = tid & 63;
    int g  = tid >> 6;           // 0..3
    float acc[8];
#pragma unroll
    for (int i = 0; i < 8; ++i) acc[i] = 0.f;

    const float4* wr = (const float4*)&Wr[ch * 128];
    const float4* wl = (const float4*)&Wl[ch * 128];
    for (int kc = 0; kc < 32; ++kc) {
        float4 wr4 = wr[kc];
        float4 wl4 = wl[kc];
#pragma unroll
        for (int i = 0; i < 8; ++i) {
            int row = g * 8 + i;
            float4 xv = ((const float4*)&xs[row][0])[kc];
            float4 mv = ((const float4*)&ms[row][0])[kc];
            acc[i] += xv.x * wr4.x + xv.y * wr4.y + xv.z * wr4.z + xv.w * wr4.w
                    + mv.x * wl4.x + mv.y * wl4.y + mv.z * wl4.z + mv.w * wl4.w;
        }
    }
    float bias = bl[ch];
#pragma unroll
    for (int i = 0; i < 8; ++i) {
        int n = base + g * 8 + i;
        if (n < nNodes) {
            z[(long long)n * 64 + ch] = acc[i] + bias;
        }
    }
}

// ---------------- decoder: out = z @ W_dec^T + b_dec ----------------
__launch_bounds__(256)
__global__ void k_dec(const float* __restrict__ z, const float* __restrict__ W,
                      const float* __restrict__ b,
                      float* __restrict__ out, int nNodes) {
    __shared__ float zs[32][64];
    int tid = threadIdx.x;
    int base = blockIdx.x * 32;

    for (int i = tid; i < 32 * 16; i += 256) {   // 512 float4
        int row = i >> 4, col4 = i & 15;
        int n = base + row;
        float4 zv = make_float4(0.f, 0.f, 0.f, 0.f);
        if (n < nNodes) zv = ((const float4*)z)[(long long)n * 16 + col4];
        ((float4*)&zs[row][0])[col4] = zv;
    }
    __syncthreads();

    int ch = tid & 127;
    int g  = tid >> 7;           // 0..1
    float acc[16];
#pragma unroll
    for (int i = 0; i < 16; ++i) acc[i] = 0.f;

    const float4* w = (const float4*)&W[ch * 64];
    for (int kc = 0; kc < 16; ++kc) {
        float4 w4 = w[kc];
#pragma unroll
        for (int i = 0; i < 16; ++i) {
            int row = g * 16 + i;
            float4 zv = ((const float4*)&zs[row][0])[kc];
            acc[i] += zv.x * w4.x + zv.y * w4.y + zv.z * w4.z + zv.w * w4.w;
        }
    }
    float bias = b[ch];
#pragma unroll
    for (int i = 0; i < 16; ++i) {
        int n = base + g * 16 + i;
        if (n < nNodes) out[(long long)n * 128 + ch] = acc[i] + bias;
    }
}

extern "C" void kernel_launch(void* const* d_in, const int* in_sizes, int n_in,
                              void* d_out, int out_size, void* d_ws, size_t ws_size,
                              hipStream_t stream) {
    const float* x    = (const float*)d_in[0];
    const int*   ei   = (const int*)d_in[1];     // int32 on device (harness converts)
    const float* W1l  = (const float*)d_in[2];
    const float* b1l  = (const float*)d_in[3];
    const float* W1r  = (const float*)d_in[4];
    const float* W2l  = (const float*)d_in[5];
    const float* b2l  = (const float*)d_in[6];
    const float* W2r  = (const float*)d_in[7];
    const float* Wdec = (const float*)d_in[8];
    const float* bdec = (const float*)d_in[9];

    const int N = in_sizes[0] / 128;
    const int E = in_sizes[1] / 2;

    const int* src = ei;
    const int* dst = ei + E;

    // workspace layout: msg [N*128] floats, then deg [N] floats
    float* msg = (float*)d_ws;
    float* deg = msg + (long long)N * 128;

    // d_out layout: x_recon [N*128] then z [N*64]. Park h in the x_recon region.
    float* outp = (float*)d_out;
    float* h    = outp;                      // temporary home for h
    float* z    = outp + (long long)N * 128;
    float* xrec = outp;

    // ---- zero msg + deg ----
    hipMemsetAsync(d_ws, 0, ((size_t)N * 128 + N) * sizeof(float), stream);

    // ---- degree ----
    k_degree<<<(E + 255) / 256, 256, 0, stream>>>(dst, deg, E, N);

    // ---- layer 1 aggregate: msg += x[src] ----
    {
        int total = E * 32;
        k_scatter128<<<(total + 255) / 256, 256, 0, stream>>>(src, dst, x, msg, E, N);
    }

    // ---- layer 1 dense: h = relu(agg@W1l^T + b1 + x@W1r^T) ----
    k_sage1<<<(N + 31) / 32, 256, 0, stream>>>(x, msg, deg, W1l, b1l, W1r, h, N);

    // ---- zero msg (keep deg) ----
    hipMemsetAsync(msg, 0, (size_t)N * 128 * sizeof(float), stream);

    // ---- layer 2 aggregate: msg += h[src] ----
    {
        int total = E * 32;
        k_scatter128<<<(total + 255) / 256, 256, 0, stream>>>(src, dst, h, msg, E, N);
    }

    // ---- layer 2 dense: z = agg@W2l^T + b2 + h@W2r^T ----
    k_sage2<<<(N + 31) / 32, 256, 0, stream>>>(h, msg, deg, W2l, b2l, W2r, z, N);

    // ---- decoder: x_recon = z@Wdec^T + bdec (overwrites h region) ----
    k_dec<<<(N + 31) / 32, 256, 0, stream>>>(z, Wdec, bdec, xrec, N);
}

// Round 3
// 849.143 us; speedup vs baseline: 6.8844x; 6.8844x over previous
//
#include <hip/hip_runtime.h>

// N = 100000 nodes, E = 1600000 edges, IN=128, HID=128, LAT=64
// edge_index arrives on device as int32 (harness converts integer inputs).
//
// Strategy: build CSR by dst (counting sort) once per call, then each SAGE
// layer GATHERS neighbor rows (no feature atomics), fused with the dense
// matmul. Only the CSR build uses atomics (1.6M int adds, cheap).

// ---------------- degree (int): deg[dst]++ ----------------
__global__ void k_deg(const int* __restrict__ dst, int* __restrict__ deg, int E, int nNodes) {
    int i = blockIdx.x * blockDim.x + threadIdx.x;
    if (i < E) {
        unsigned d = (unsigned)dst[i];
        if (d < (unsigned)nNodes) atomicAdd(&deg[d], 1);
    }
}

// ---------------- scan stage 1: per-256-chunk exclusive scan + chunk totals ----------------
__global__ void k_scan1(const int* __restrict__ deg, int* __restrict__ off,
                        int* __restrict__ bs, int nNodes) {
    __shared__ int tmp[256];
    int t = threadIdx.x;
    int i = blockIdx.x * 256 + t;
    int v = (i < nNodes) ? deg[i] : 0;
    tmp[t] = v;
    __syncthreads();
    for (int d = 1; d < 256; d <<= 1) {
        int add = (t >= d) ? tmp[t - d] : 0;
        __syncthreads();
        tmp[t] += add;
        __syncthreads();
    }
    if (i < nNodes) off[i] = tmp[t] - v;      // exclusive within chunk
    if (t == 255) bs[blockIdx.x] = tmp[255];  // chunk total
}

// ---------------- scan stage 2: exclusive scan of chunk totals (1 block) ----------------
__global__ void k_scan2(int* __restrict__ bs, int nb) {
    __shared__ int tmp[512];
    int t = threadIdx.x;  // 512 threads
    int carry = 0;
    for (int start = 0; start < nb; start += 512) {
        int i = start + t;
        int v = (i < nb) ? bs[i] : 0;
        tmp[t] = v;
        __syncthreads();
        for (int d = 1; d < 512; d <<= 1) {
            int add = (t >= d) ? tmp[t - d] : 0;
            __syncthreads();
            tmp[t] += add;
            __syncthreads();
        }
        int incl = tmp[t];
        if (i < nb) bs[i] = incl - v + carry;  // exclusive + carry
        int total = tmp[511];
        __syncthreads();
        carry += total;
    }
}

// ---------------- scan stage 3: add chunk bases ----------------
__global__ void k_scan3(int* __restrict__ off, const int* __restrict__ bs, int nNodes) {
    int i = blockIdx.x * 256 + threadIdx.x;
    if (i < nNodes) off[i] += bs[blockIdx.x];
}

// ---------------- CSR fill: adj[off[d] + cur[d]++] = s ----------------
__global__ void k_fill(const int* __restrict__ src, const int* __restrict__ dst,
                       const int* __restrict__ off, int* __restrict__ cur,
                       int* __restrict__ adj, int E, int nNodes) {
    int i = blockIdx.x * blockDim.x + threadIdx.x;
    if (i < E) {
        unsigned d = (unsigned)dst[i];
        unsigned s = (unsigned)src[i];
        if (d < (unsigned)nNodes && s < (unsigned)nNodes) {
            int pos = atomicAdd(&cur[d], 1);
            adj[off[d] + pos] = (int)s;
        }
    }
}

// ---------------- fused gather + SAGE layer 1 ----------------
// 32 nodes/block, 256 threads (4 waves). Phase A: stage x rows + gather-mean
// neighbor rows into LDS. Phase B: h = relu(agg@W1l^T + b1 + x@W1r^T).
__launch_bounds__(256)
__global__ void k_sage1(const float* __restrict__ x,
                        const int* __restrict__ adj, const int* __restrict__ off,
                        const int* __restrict__ deg,
                        const float* __restrict__ Wl, const float* __restrict__ bl,
                        const float* __restrict__ Wr,
                        float* __restrict__ h, int nNodes) {
    __shared__ float xs[32][128];
    __shared__ float ms[32][128];
    int tid = threadIdx.x;
    int base = blockIdx.x * 32;

    // stage self rows
    for (int i = tid; i < 32 * 32; i += 256) {
        int row = i >> 5, col4 = i & 31;
        int n = base + row;
        float4 xv = make_float4(0.f, 0.f, 0.f, 0.f);
        if (n < nNodes) xv = ((const float4*)x)[(long long)n * 32 + col4];
        ((float4*)&xs[row][0])[col4] = xv;
    }

    // gather-mean neighbors: wave w handles nodes w*8 .. w*8+7
    int w = tid >> 6, lane = tid & 63;
    int half = lane >> 5, l32 = lane & 31;
    const float4* feat4 = (const float4*)x;
    for (int r = w * 8; r < w * 8 + 8; ++r) {
        int n = base + r;
        float4 a = make_float4(0.f, 0.f, 0.f, 0.f);
        float inv = 1.f;
        if (n < nNodes) {
            int o0 = off[n];
            int dg = deg[n];
            int o1 = o0 + dg;
            for (int k = o0 + half; k < o1; k += 2) {  // halves take even/odd nbrs
                int s = adj[k];
                float4 v = feat4[(long long)s * 32 + l32];
                a.x += v.x; a.y += v.y; a.z += v.z; a.w += v.w;
            }
            inv = 1.f / fmaxf((float)dg, 1.f);
        }
        a.x += __shfl_xor(a.x, 32);
        a.y += __shfl_xor(a.y, 32);
        a.z += __shfl_xor(a.z, 32);
        a.w += __shfl_xor(a.w, 32);
        if (half == 0) {
            a.x *= inv; a.y *= inv; a.z *= inv; a.w *= inv;
            ((float4*)&ms[r][0])[l32] = a;
        }
    }
    __syncthreads();

    // dense: 128 ch x 2 node-groups, 16 nodes/thread
    int ch = tid & 127;
    int g  = tid >> 7;
    float acc[16];
#pragma unroll
    for (int i = 0; i < 16; ++i) acc[i] = 0.f;

    const float4* wr = (const float4*)&Wr[ch * 128];
    const float4* wl = (const float4*)&Wl[ch * 128];
    for (int kc = 0; kc < 32; ++kc) {
        float4 wr4 = wr[kc];
        float4 wl4 = wl[kc];
#pragma unroll
        for (int i = 0; i < 16; ++i) {
            int row = g * 16 + i;
            float4 xv = ((const float4*)&xs[row][0])[kc];
            float4 mv = ((const float4*)&ms[row][0])[kc];
            acc[i] += xv.x * wr4.x + xv.y * wr4.y + xv.z * wr4.z + xv.w * wr4.w
                    + mv.x * wl4.x + mv.y * wl4.y + mv.z * wl4.z + mv.w * wl4.w;
        }
    }
    float bias = bl[ch];
#pragma unroll
    for (int i = 0; i < 16; ++i) {
        int n = base + g * 16 + i;
        if (n < nNodes) h[(long long)n * 128 + ch] = fmaxf(acc[i] + bias, 0.f);
    }
}

// ---------------- fused gather + SAGE layer 2 (64 out ch, no relu) ----------------
__launch_bounds__(256)
__global__ void k_sage2(const float* __restrict__ hin,
                        const int* __restrict__ adj, const int* __restrict__ off,
                        const int* __restrict__ deg,
                        const float* __restrict__ Wl, const float* __restrict__ bl,
                        const float* __restrict__ Wr,
                        float* __restrict__ z, int nNodes) {
    __shared__ float xs[32][128];
    __shared__ float ms[32][128];
    int tid = threadIdx.x;
    int base = blockIdx.x * 32;

    for (int i = tid; i < 32 * 32; i += 256) {
        int row = i >> 5, col4 = i & 31;
        int n = base + row;
        float4 xv = make_float4(0.f, 0.f, 0.f, 0.f);
        if (n < nNodes) xv = ((const float4*)hin)[(long long)n * 32 + col4];
        ((float4*)&xs[row][0])[col4] = xv;
    }

    int w = tid >> 6, lane = tid & 63;
    int half = lane >> 5, l32 = lane & 31;
    const float4* feat4 = (const float4*)hin;
    for (int r = w * 8; r < w * 8 + 8; ++r) {
        int n = base + r;
        float4 a = make_float4(0.f, 0.f, 0.f, 0.f);
        float inv = 1.f;
        if (n < nNodes) {
            int o0 = off[n];
            int dg = deg[n];
            int o1 = o0 + dg;
            for (int k = o0 + half; k < o1; k += 2) {
                int s = adj[k];
                float4 v = feat4[(long long)s * 32 + l32];
                a.x += v.x; a.y += v.y; a.z += v.z; a.w += v.w;
            }
            inv = 1.f / fmaxf((float)dg, 1.f);
        }
        a.x += __shfl_xor(a.x, 32);
        a.y += __shfl_xor(a.y, 32);
        a.z += __shfl_xor(a.z, 32);
        a.w += __shfl_xor(a.w, 32);
        if (half == 0) {
            a.x *= inv; a.y *= inv; a.z *= inv; a.w *= inv;
            ((float4*)&ms[r][0])[l32] = a;
        }
    }
    __syncthreads();

    // dense: 64 ch x 4 node-groups, 8 nodes/thread
    int ch = tid & 63;
    int g  = tid >> 6;
    float acc[8];
#pragma unroll
    for (int i = 0; i < 8; ++i) acc[i] = 0.f;

    const float4* wr = (const float4*)&Wr[ch * 128];
    const float4* wl = (const float4*)&Wl[ch * 128];
    for (int kc = 0; kc < 32; ++kc) {
        float4 wr4 = wr[kc];
        float4 wl4 = wl[kc];
#pragma unroll
        for (int i = 0; i < 8; ++i) {
            int row = g * 8 + i;
            float4 xv = ((const float4*)&xs[row][0])[kc];
            float4 mv = ((const float4*)&ms[row][0])[kc];
            acc[i] += xv.x * wr4.x + xv.y * wr4.y + xv.z * wr4.z + xv.w * wr4.w
                    + mv.x * wl4.x + mv.y * wl4.y + mv.z * wl4.z + mv.w * wl4.w;
        }
    }
    float bias = bl[ch];
#pragma unroll
    for (int i = 0; i < 8; ++i) {
        int n = base + g * 8 + i;
        if (n < nNodes) z[(long long)n * 64 + ch] = acc[i] + bias;
    }
}

// ---------------- decoder: out = z @ W_dec^T + b_dec ----------------
__launch_bounds__(256)
__global__ void k_dec(const float* __restrict__ z, const float* __restrict__ W,
                      const float* __restrict__ b,
                      float* __restrict__ out, int nNodes) {
    __shared__ float zs[32][64];
    int tid = threadIdx.x;
    int base = blockIdx.x * 32;

    for (int i = tid; i < 32 * 16; i += 256) {
        int row = i >> 4, col4 = i & 15;
        int n = base + row;
        float4 zv = make_float4(0.f, 0.f, 0.f, 0.f);
        if (n < nNodes) zv = ((const float4*)z)[(long long)n * 16 + col4];
        ((float4*)&zs[row][0])[col4] = zv;
    }
    __syncthreads();

    int ch = tid & 127;
    int g  = tid >> 7;
    float acc[16];
#pragma unroll
    for (int i = 0; i < 16; ++i) acc[i] = 0.f;

    const float4* w = (const float4*)&W[ch * 64];
    for (int kc = 0; kc < 16; ++kc) {
        float4 w4 = w[kc];
#pragma unroll
        for (int i = 0; i < 16; ++i) {
            int row = g * 16 + i;
            float4 zv = ((const float4*)&zs[row][0])[kc];
            acc[i] += zv.x * w4.x + zv.y * w4.y + zv.z * w4.z + zv.w * w4.w;
        }
    }
    float bias = b[ch];
#pragma unroll
    for (int i = 0; i < 16; ++i) {
        int n = base + g * 16 + i;
        if (n < nNodes) out[(long long)n * 128 + ch] = acc[i] + bias;
    }
}

extern "C" void kernel_launch(void* const* d_in, const int* in_sizes, int n_in,
                              void* d_out, int out_size, void* d_ws, size_t ws_size,
                              hipStream_t stream) {
    const float* x    = (const float*)d_in[0];
    const int*   ei   = (const int*)d_in[1];   // int32 on device
    const float* W1l  = (const float*)d_in[2];
    const float* b1l  = (const float*)d_in[3];
    const float* W1r  = (const float*)d_in[4];
    const float* W2l  = (const float*)d_in[5];
    const float* b2l  = (const float*)d_in[6];
    const float* W2r  = (const float*)d_in[7];
    const float* Wdec = (const float*)d_in[8];
    const float* bdec = (const float*)d_in[9];

    const int N = in_sizes[0] / 128;
    const int E = in_sizes[1] / 2;
    const int nb = (N + 255) / 256;

    const int* src = ei;
    const int* dst = ei + E;

    // ws layout (ints): adj[E] | deg[N] | cur[N] | off[N] | bs[nb]
    int* adj = (int*)d_ws;
    int* deg = adj + E;
    int* cur = deg + N;
    int* off = cur + N;
    int* bs  = off + N;

    // zero deg + cur (contiguous)
    hipMemsetAsync(deg, 0, (size_t)2 * N * sizeof(int), stream);

    // CSR build
    k_deg  <<<(E + 255) / 256, 256, 0, stream>>>(dst, deg, E, N);
    k_scan1<<<nb, 256, 0, stream>>>(deg, off, bs, N);
    k_scan2<<<1, 512, 0, stream>>>(bs, nb);
    k_scan3<<<nb, 256, 0, stream>>>(off, bs, N);
    k_fill <<<(E + 255) / 256, 256, 0, stream>>>(src, dst, off, cur, adj, E, N);

    // d_out layout: x_recon [N*128] then z [N*64]; park h in x_recon region
    float* outp = (float*)d_out;
    float* h    = outp;
    float* z    = outp + (long long)N * 128;
    float* xrec = outp;

    const int nblk = (N + 31) / 32;
    k_sage1<<<nblk, 256, 0, stream>>>(x, adj, off, deg, W1l, b1l, W1r, h, N);
    k_sage2<<<nblk, 256, 0, stream>>>(h, adj, off, deg, W2l, b2l, W2r, z, N);
    k_dec  <<<nblk, 256, 0, stream>>>(z, Wdec, bdec, xrec, N);
}